// Round 5
// baseline (1950.500 us; speedup 1.0000x reference)
//
#include <hip/hip_runtime.h>
#include <hip/hip_bf16.h>
#include <stdint.h>

// fSRN: fused SIREN + 3 forward-mode tangent streams, MFMA engine, v5.
// WG = 256 threads (4 waves), 32 points. A = 128 rows (4 streams x 32 pts)
// x 128 features, bf16 in LDS, XOR-chunk swizzle. Wave (wm,wn) computes the
// 64x64 output tile rows [wm*64,+64) x cols [wn*64,+64): 4x4x4 mfma 16x16x32.
// 76.4 KB LDS -> 2 WGs/CU.
// v5 vs v4: register-pressure capping. v4 spilled mst around each gemm
// (894 MB deterministic scratch writes/dispatch) because the scheduler
// interleaved ~32 sincos chains on top of mst(64)+acc(64) under the
// 256-reg cap from __launch_bounds__(256,2). Fixes:
//   - sched_barrier(0) after each nt-group in heavy VALU phases (loops stay
//     fully unrolled -> register indices stay compile-time, rule #20 safe)
//   - __sincosf (one range reduction for sin+cos)
//   - stageW unroll 2 (<=2 float4 loads in flight, was 8)

#define OMEGA_C 30.0f

constexpr int NPTS = 131072;
constexpr int FDIM = 128;
constexpr int NBLK = 3;
constexpr int P_WG = 32;
constexpr int NTHR = 256;   // 4 waves

typedef short bf16x8 __attribute__((ext_vector_type(8)));
typedef float f32x4  __attribute__((ext_vector_type(4)));

__device__ __forceinline__ uint32_t bfbits(float f) {
    union { float f; uint32_t u; } x; x.f = f;
    uint32_t u = x.u;
    return (u + 0x7FFFu + ((u >> 16) & 1u)) >> 16;   // RNE
}
__device__ __forceinline__ float u16tof(uint16_t h) {
    union { uint32_t u; float f; } x; x.u = ((uint32_t)h) << 16; return x.f;
}

// swizzled byte offset into a [rows][128] bf16 tile with 256 B rows
__device__ __forceinline__ int swz(int row, int col) {
    const int b = col << 1;
    return (row << 8) + ((((b >> 4) ^ (row & 15)) << 4) | (b & 15));
}

__global__ __launch_bounds__(NTHR, 2) void fsrn_kernel(
    const float* __restrict__ coords,
    const float* __restrict__ first_w,
    const float* __restrict__ first_b,
    const float* __restrict__ res_w1,
    const float* __restrict__ res_b1,
    const float* __restrict__ res_w2,
    const float* __restrict__ res_b2,
    const float* __restrict__ final_w,
    float* __restrict__ out)
{
    __shared__ __align__(16) uint8_t A8[128 * 256];   // 32 KiB activations
    __shared__ __align__(16) uint8_t W8[128 * 256];   // 32 KiB weights
    __shared__ __align__(16) uint8_t C8[32 * 256];    //  8 KiB OMEGA*cos
    __shared__ float xyz[P_WG * 3];
    __shared__ float outp[3][2][P_WG][3];

    const int tid  = threadIdx.x;
    const int wave = tid >> 6;
    const int lane = tid & 63;
    const int l15  = lane & 15;
    const int lq   = lane >> 4;            // 0..3
    const int wm   = wave >> 1;            // 0: rows 0..63 (primal+dx), 1: rows 64..127 (dy+dz)
    const int wn   = wave & 1;             // col-half
    const int rowbase = wm * 64;
    const int colbase = wn * 64;
    const int pt0  = blockIdx.x * P_WG;

    float mst[4][4][4];    // master state (h / dh), fp32 [mt][nt][j] — static idx ONLY
    f32x4 acc[4][4];       // MFMA accumulators [mt][nt] — static idx ONLY

    if (tid < P_WG * 3) xyz[tid] = coords[pt0 * 3 + tid];

    auto stageW = [&](const float* __restrict__ src, float scale) {
        #pragma unroll 2
        for (int i = 0; i < 8; ++i) {
            const int g   = tid + (i << 8);        // chunk id 0..2047
            const int row = g >> 4, c = g & 15;
            const float4 v0 = *reinterpret_cast<const float4*>(src + (g << 3));
            const float4 v1 = *reinterpret_cast<const float4*>(src + (g << 3) + 4);
            uint4 w;
            w.x = bfbits(scale*v0.x) | (bfbits(scale*v0.y) << 16);
            w.y = bfbits(scale*v0.z) | (bfbits(scale*v0.w) << 16);
            w.z = bfbits(scale*v1.x) | (bfbits(scale*v1.y) << 16);
            w.w = bfbits(scale*v1.z) | (bfbits(scale*v1.w) << 16);
            *reinterpret_cast<uint4*>(W8 + (row << 8) + (((c ^ (row & 15)) << 4))) = w;
        }
    };

    stageW(res_w1, 1.0f);      // block 0 layer 1 (s=1)
    __syncthreads();

    // ---- first layer ----
    #pragma unroll
    for (int mt = 0; mt < 4; ++mt) {
        const int s_mt = 2*wm + (mt >> 1);
        #pragma unroll
        for (int nt = 0; nt < 4; ++nt) {
            const int f = colbase + nt*16 + l15;
            const float w0 = first_w[f*3+0], w1 = first_w[f*3+1], w2 = first_w[f*3+2];
            const float fb = first_b[f];
            const float wk = (s_mt == 1) ? w0 : (s_mt == 2) ? w1 : w2;
            #pragma unroll
            for (int j = 0; j < 4; ++j) {
                const int p = (mt & 1)*16 + lq*4 + j;
                const float pre = OMEGA_C * (xyz[p*3]*w0 + xyz[p*3+1]*w1 + xyz[p*3+2]*w2 + fb);
                const float v = (s_mt == 0) ? __sinf(pre) : OMEGA_C * __cosf(pre) * wk;
                mst[mt][nt][j] = v;
                *reinterpret_cast<uint16_t*>(A8 + swz(rowbase + mt*16 + lq*4 + j, f))
                    = (uint16_t)bfbits(v);
            }
            __builtin_amdgcn_sched_barrier(0);   // cap live sincos chains
        }
    }
    __syncthreads();

    auto gemm = [&]() {
        #pragma unroll
        for (int mt = 0; mt < 4; ++mt)
            #pragma unroll
            for (int nt = 0; nt < 4; ++nt) acc[mt][nt] = f32x4{0.f,0.f,0.f,0.f};
        #pragma unroll
        for (int kk = 0; kk < 4; ++kk) {
            bf16x8 af[4];
            #pragma unroll
            for (int mt = 0; mt < 4; ++mt)
                af[mt] = *reinterpret_cast<const bf16x8*>(
                    A8 + swz(rowbase + mt*16 + l15, kk*32 + lq*8));
            #pragma unroll
            for (int nt = 0; nt < 4; ++nt) {
                const bf16x8 wf = *reinterpret_cast<const bf16x8*>(
                    W8 + swz(colbase + nt*16 + l15, kk*32 + lq*8));
                #pragma unroll
                for (int mt = 0; mt < 4; ++mt)
                    acc[mt][nt] = __builtin_amdgcn_mfma_f32_16x16x32_bf16(af[mt], wf, acc[mt][nt], 0, 0, 0);
            }
        }
    };

    #pragma unroll 1
    for (int b = 0; b < NBLK; ++b) {
        // ================= sub-layer 1: W = s*w1[b] =================
        gemm();
        if (wm == 0) {   // primal: sincos; publish cos (C8 not read by gemm);
                         // stage sin in acc (A8 write deferred past barrier)
            #pragma unroll
            for (int mt = 0; mt < 2; ++mt)
                #pragma unroll
                for (int nt = 0; nt < 4; ++nt) {
                    const int f = colbase + nt*16 + l15;
                    const float ob = OMEGA_C * res_b1[b*FDIM + f];
                    #pragma unroll
                    for (int j = 0; j < 4; ++j) {
                        const int p = mt*16 + lq*4 + j;
                        const float pre = OMEGA_C * acc[mt][nt][j] + ob;
                        float sv, cv;
                        __sincosf(pre, &sv, &cv);
                        *reinterpret_cast<uint16_t*>(C8 + swz(p, f))
                            = (uint16_t)bfbits(OMEGA_C * cv);
                        acc[mt][nt][j] = sv;
                    }
                    __builtin_amdgcn_sched_barrier(0);
                }
        }
        __syncthreads();   // all gemm A8/W8 reads done; C8 visible
        if (wm == 0) {     // write primal A rows
            #pragma unroll
            for (int mt = 0; mt < 2; ++mt)
                #pragma unroll
                for (int nt = 0; nt < 4; ++nt) {
                    const int f = colbase + nt*16 + l15;
                    #pragma unroll
                    for (int j = 0; j < 4; ++j)
                        *reinterpret_cast<uint16_t*>(A8 + swz(mt*16 + lq*4 + j, f))
                            = (uint16_t)bfbits(acc[mt][nt][j]);
                }
        }
        #pragma unroll
        for (int mt = 0; mt < 4; ++mt) {       // tangent rows (static mt, uniform guard)
            if (wm == 1 || mt >= 2) {
                #pragma unroll
                for (int nt = 0; nt < 4; ++nt) {
                    const int f = colbase + nt*16 + l15;
                    #pragma unroll
                    for (int j = 0; j < 4; ++j) {
                        const int p = (mt & 1)*16 + lq*4 + j;
                        const float cv = u16tof(*reinterpret_cast<const uint16_t*>(C8 + swz(p, f)));
                        const float v = cv * acc[mt][nt][j];
                        *reinterpret_cast<uint16_t*>(A8 + swz(rowbase + mt*16 + lq*4 + j, f))
                            = (uint16_t)bfbits(v);
                    }
                    __builtin_amdgcn_sched_barrier(0);
                }
            }
        }
        stageW(res_w2 + b*FDIM*FDIM, 1.0f);
        __syncthreads();

        // ================= sub-layer 2: W = w2[b], residual =================
        gemm();
        if (wm == 0) {
            #pragma unroll
            for (int mt = 0; mt < 2; ++mt)
                #pragma unroll
                for (int nt = 0; nt < 4; ++nt) {
                    const int f = colbase + nt*16 + l15;
                    const float ob = OMEGA_C * res_b2[b*FDIM + f];
                    #pragma unroll
                    for (int j = 0; j < 4; ++j) {
                        const int p = mt*16 + lq*4 + j;
                        const float pre = OMEGA_C * acc[mt][nt][j] + ob;
                        float sv, cv;
                        __sincosf(pre, &sv, &cv);
                        *reinterpret_cast<uint16_t*>(C8 + swz(p, f))
                            = (uint16_t)bfbits(OMEGA_C * cv);
                        mst[mt][nt][j] += sv;
                        acc[mt][nt][j] = mst[mt][nt][j];
                    }
                    __builtin_amdgcn_sched_barrier(0);
                }
        }
        __syncthreads();
        if (wm == 0) {
            #pragma unroll
            for (int mt = 0; mt < 2; ++mt)
                #pragma unroll
                for (int nt = 0; nt < 4; ++nt) {
                    const int f = colbase + nt*16 + l15;
                    #pragma unroll
                    for (int j = 0; j < 4; ++j)
                        *reinterpret_cast<uint16_t*>(A8 + swz(mt*16 + lq*4 + j, f))
                            = (uint16_t)bfbits(acc[mt][nt][j]);
                }
        }
        #pragma unroll
        for (int mt = 0; mt < 4; ++mt) {
            if (wm == 1 || mt >= 2) {
                #pragma unroll
                for (int nt = 0; nt < 4; ++nt) {
                    const int f = colbase + nt*16 + l15;
                    #pragma unroll
                    for (int j = 0; j < 4; ++j) {
                        const int p = (mt & 1)*16 + lq*4 + j;
                        const float cv = u16tof(*reinterpret_cast<const uint16_t*>(C8 + swz(p, f)));
                        mst[mt][nt][j] += cv * acc[mt][nt][j];
                        *reinterpret_cast<uint16_t*>(A8 + swz(rowbase + mt*16 + lq*4 + j, f))
                            = (uint16_t)bfbits(mst[mt][nt][j]);
                    }
                    __builtin_amdgcn_sched_barrier(0);
                }
            }
        }
        if (b < NBLK-1) stageW(res_w1 + (b+1)*FDIM*FDIM, 0.5f);   // s=0.5 folded
        __syncthreads();
    }

    // ---- final: out[:,c] = signed combos of dh_k . final_w[row] ----
    #pragma unroll
    for (int mt = 0; mt < 4; ++mt) {
        if (wm == 1 || mt >= 2) {
            const int k = 2*wm + (mt >> 1) - 1;   // wave-uniform
            #pragma unroll
            for (int c = 0; c < 3; ++c) {
                int wr; float sg;
                if (c == 0)      { wr = (k==0)?0:(k==1)?3:2; sg = (k==2)?-1.f:1.f; }
                else if (c == 1) { wr = (k==0)?3:(k==1)?0:1; sg = (k==0)?-1.f:1.f; }
                else             { wr = (k==0)?2:(k==1)?1:0; sg = (k==1)?-1.f:1.f; }
                float fwv[4];
                #pragma unroll
                for (int nt = 0; nt < 4; ++nt)
                    fwv[nt] = final_w[wr*FDIM + colbase + nt*16 + l15];
                #pragma unroll
                for (int j = 0; j < 4; ++j) {
                    float part = 0.0f;
                    #pragma unroll
                    for (int nt = 0; nt < 4; ++nt) part += mst[mt][nt][j] * fwv[nt];
                    part += __shfl_xor(part, 1);
                    part += __shfl_xor(part, 2);
                    part += __shfl_xor(part, 4);
                    part += __shfl_xor(part, 8);
                    if (l15 == 0) outp[k][wn][(mt & 1)*16 + lq*4 + j][c] = sg * part;
                }
                __builtin_amdgcn_sched_barrier(0);
            }
        }
    }
    __syncthreads();

    if (tid < P_WG * 3) {
        const int p = tid / 3, c = tid % 3;
        out[(pt0 + p)*3 + c] = outp[0][0][p][c] + outp[0][1][p][c]
                             + outp[1][0][p][c] + outp[1][1][p][c]
                             + outp[2][0][p][c] + outp[2][1][p][c];
    }
}

extern "C" void kernel_launch(void* const* d_in, const int* in_sizes, int n_in,
                              void* d_out, int out_size, void* d_ws, size_t ws_size,
                              hipStream_t stream) {
    const float* coords  = (const float*)d_in[0];
    const float* first_w = (const float*)d_in[1];
    const float* first_b = (const float*)d_in[2];
    const float* res_w1  = (const float*)d_in[3];
    const float* res_b1  = (const float*)d_in[4];
    const float* res_w2  = (const float*)d_in[5];
    const float* res_b2  = (const float*)d_in[6];
    const float* final_w = (const float*)d_in[7];
    // final_b (d_in[8]) does not influence the Jacobian -> unused.

    dim3 grid(NPTS / P_WG);   // 4096 workgroups
    fsrn_kernel<<<grid, NTHR, 0, stream>>>(coords, first_w, first_b,
                                           res_w1, res_b1, res_w2, res_b2,
                                           final_w, (float*)d_out);
}

// Round 7
// 1238.600 us; speedup vs baseline: 1.5748x; 1.5748x over previous
//
#include <hip/hip_runtime.h>
#include <hip/hip_bf16.h>
#include <stdint.h>

// fSRN: fused SIREN + 3 forward-mode tangent streams, MFMA engine, v6.
// (Resubmission — round 6 bench failed with GPUAcquisitionTimeout before
// running; no counters were produced.)
// WG = 512 threads (8 waves), 32 points. A = 128 rows (4 streams x 32 pts)
// x 128 features, bf16 in LDS, XOR-chunk swizzle.
// Wave grid 2x4: wm = wave>>2 -> rows [wm*64,+64); wn = wave&3 -> cols
// [wn*32,+32). Per wave: 4mt x 2nt x 4kk mfma 16x16x32.
// Per-thread persistent state HALVED vs v3-v5: mst[4][2][4]=32 f32,
// acc[4][2]=32 f32  (v3-v5's 64+64 exceeded the allocator's budget ->
// deterministic 0.6-0.9 GB scratch spill traffic per dispatch).
// LDS 78.7 KB -> 2 WGs/CU; __launch_bounds__(512,4) caps regs at 128 to
// guarantee 16 waves/CU.

#define OMEGA_C 30.0f

constexpr int NPTS = 131072;
constexpr int FDIM = 128;
constexpr int NBLK = 3;
constexpr int P_WG = 32;
constexpr int NTHR = 512;   // 8 waves

typedef short bf16x8 __attribute__((ext_vector_type(8)));
typedef float f32x4  __attribute__((ext_vector_type(4)));

__device__ __forceinline__ uint32_t bfbits(float f) {
    union { float f; uint32_t u; } x; x.f = f;
    uint32_t u = x.u;
    return (u + 0x7FFFu + ((u >> 16) & 1u)) >> 16;   // RNE
}
__device__ __forceinline__ float u16tof(uint16_t h) {
    union { uint32_t u; float f; } x; x.u = ((uint32_t)h) << 16; return x.f;
}

// swizzled byte offset into a [rows][128] bf16 tile with 256 B rows:
// 16B chunk index XORed with (row & 15) -> aligned b128 reads stay 2-way,
// scalar b16 stores spread across banks.
__device__ __forceinline__ int swz(int row, int col) {
    const int b = col << 1;
    return (row << 8) + ((((b >> 4) ^ (row & 15)) << 4) | (b & 15));
}

__global__ __launch_bounds__(NTHR, 4) void fsrn_kernel(
    const float* __restrict__ coords,
    const float* __restrict__ first_w,
    const float* __restrict__ first_b,
    const float* __restrict__ res_w1,
    const float* __restrict__ res_b1,
    const float* __restrict__ res_w2,
    const float* __restrict__ res_b2,
    const float* __restrict__ final_w,
    float* __restrict__ out)
{
    __shared__ __align__(16) uint8_t A8[128 * 256];   // 32 KiB activations
    __shared__ __align__(16) uint8_t W8[128 * 256];   // 32 KiB weights
    __shared__ __align__(16) uint8_t C8[32 * 256];    //  8 KiB OMEGA*cos
    __shared__ float xyz[P_WG * 3];                   // 384 B
    __shared__ float outp[3][4][P_WG][3];             // 4608 B

    const int tid  = threadIdx.x;
    const int wave = tid >> 6;
    const int lane = tid & 63;
    const int l15  = lane & 15;
    const int lq   = lane >> 4;            // 0..3
    const int wm   = wave >> 2;            // 0: rows 0..63 (primal+dx), 1: rows 64..127 (dy+dz)
    const int wn   = wave & 3;             // col quarter
    const int rowbase = wm * 64;
    const int colbase = wn * 32;
    const int pt0  = blockIdx.x * P_WG;

    float mst[4][2][4];    // master state (h / dh), fp32 [mt][nt][j] — static idx ONLY
    f32x4 acc[4][2];       // MFMA accumulators [mt][nt] — static idx ONLY

    if (tid < P_WG * 3) xyz[tid] = coords[pt0 * 3 + tid];

    auto stageW = [&](const float* __restrict__ src, float scale) {
        #pragma unroll 2
        for (int i = 0; i < 4; ++i) {
            const int g   = tid + (i << 9);        // chunk id 0..2047
            const int row = g >> 4, c = g & 15;
            const float4 v0 = *reinterpret_cast<const float4*>(src + (g << 3));
            const float4 v1 = *reinterpret_cast<const float4*>(src + (g << 3) + 4);
            uint4 w;
            w.x = bfbits(scale*v0.x) | (bfbits(scale*v0.y) << 16);
            w.y = bfbits(scale*v0.z) | (bfbits(scale*v0.w) << 16);
            w.z = bfbits(scale*v1.x) | (bfbits(scale*v1.y) << 16);
            w.w = bfbits(scale*v1.z) | (bfbits(scale*v1.w) << 16);
            *reinterpret_cast<uint4*>(W8 + (row << 8) + (((c ^ (row & 15)) << 4))) = w;
        }
    };

    stageW(res_w1, 1.0f);      // block 0 layer 1 (s=1)
    __syncthreads();

    // ---- first layer ----
    #pragma unroll
    for (int mt = 0; mt < 4; ++mt) {
        const int s_mt = 2*wm + (mt >> 1);     // wave-uniform
        #pragma unroll
        for (int nt = 0; nt < 2; ++nt) {
            const int f = colbase + nt*16 + l15;
            const float w0 = first_w[f*3+0], w1 = first_w[f*3+1], w2 = first_w[f*3+2];
            const float fb = first_b[f];
            const float wk = (s_mt == 1) ? w0 : (s_mt == 2) ? w1 : w2;
            #pragma unroll
            for (int j = 0; j < 4; ++j) {
                const int p = (mt & 1)*16 + lq*4 + j;
                const float pre = OMEGA_C * (xyz[p*3]*w0 + xyz[p*3+1]*w1 + xyz[p*3+2]*w2 + fb);
                const float v = (s_mt == 0) ? __sinf(pre) : OMEGA_C * __cosf(pre) * wk;
                mst[mt][nt][j] = v;
                *reinterpret_cast<uint16_t*>(A8 + swz(rowbase + mt*16 + lq*4 + j, f))
                    = (uint16_t)bfbits(v);
            }
            __builtin_amdgcn_sched_barrier(0);
        }
    }
    __syncthreads();

    auto gemm = [&]() {
        #pragma unroll
        for (int mt = 0; mt < 4; ++mt)
            #pragma unroll
            for (int nt = 0; nt < 2; ++nt) acc[mt][nt] = f32x4{0.f,0.f,0.f,0.f};
        #pragma unroll
        for (int kk = 0; kk < 4; ++kk) {
            bf16x8 af[4];
            #pragma unroll
            for (int mt = 0; mt < 4; ++mt)
                af[mt] = *reinterpret_cast<const bf16x8*>(
                    A8 + swz(rowbase + mt*16 + l15, kk*32 + lq*8));
            #pragma unroll
            for (int nt = 0; nt < 2; ++nt) {
                const bf16x8 wf = *reinterpret_cast<const bf16x8*>(
                    W8 + swz(colbase + nt*16 + l15, kk*32 + lq*8));
                #pragma unroll
                for (int mt = 0; mt < 4; ++mt)
                    acc[mt][nt] = __builtin_amdgcn_mfma_f32_16x16x32_bf16(af[mt], wf, acc[mt][nt], 0, 0, 0);
            }
        }
    };

    #pragma unroll 1
    for (int b = 0; b < NBLK; ++b) {
        // ================= sub-layer 1: W = s*w1[b] =================
        gemm();
        if (wm == 0) {   // primal rows (mt 0..1): sincos; publish cos (C8 not
                         // read by gemm); stage sin in acc (A8 write deferred)
            #pragma unroll
            for (int mt = 0; mt < 2; ++mt)
                #pragma unroll
                for (int nt = 0; nt < 2; ++nt) {
                    const int f = colbase + nt*16 + l15;
                    const float ob = OMEGA_C * res_b1[b*FDIM + f];
                    #pragma unroll
                    for (int j = 0; j < 4; ++j) {
                        const int p = mt*16 + lq*4 + j;
                        const float pre = OMEGA_C * acc[mt][nt][j] + ob;
                        float sv, cv;
                        __sincosf(pre, &sv, &cv);
                        *reinterpret_cast<uint16_t*>(C8 + swz(p, f))
                            = (uint16_t)bfbits(OMEGA_C * cv);
                        acc[mt][nt][j] = sv;
                    }
                    __builtin_amdgcn_sched_barrier(0);
                }
        }
        __syncthreads();   // all gemm A8/W8 reads done; C8 visible
        if (wm == 0) {     // write primal A rows
            #pragma unroll
            for (int mt = 0; mt < 2; ++mt)
                #pragma unroll
                for (int nt = 0; nt < 2; ++nt) {
                    const int f = colbase + nt*16 + l15;
                    #pragma unroll
                    for (int j = 0; j < 4; ++j)
                        *reinterpret_cast<uint16_t*>(A8 + swz(mt*16 + lq*4 + j, f))
                            = (uint16_t)bfbits(acc[mt][nt][j]);
                }
        }
        #pragma unroll
        for (int mt = 0; mt < 4; ++mt) {       // tangent rows
            if (wm == 1 || mt >= 2) {
                #pragma unroll
                for (int nt = 0; nt < 2; ++nt) {
                    const int f = colbase + nt*16 + l15;
                    #pragma unroll
                    for (int j = 0; j < 4; ++j) {
                        const int p = (mt & 1)*16 + lq*4 + j;
                        const float cv = u16tof(*reinterpret_cast<const uint16_t*>(C8 + swz(p, f)));
                        const float v = cv * acc[mt][nt][j];
                        *reinterpret_cast<uint16_t*>(A8 + swz(rowbase + mt*16 + lq*4 + j, f))
                            = (uint16_t)bfbits(v);
                    }
                }
                __builtin_amdgcn_sched_barrier(0);
            }
        }
        stageW(res_w2 + b*FDIM*FDIM, 1.0f);
        __syncthreads();

        // ================= sub-layer 2: W = w2[b], residual =================
        gemm();
        if (wm == 0) {
            #pragma unroll
            for (int mt = 0; mt < 2; ++mt)
                #pragma unroll
                for (int nt = 0; nt < 2; ++nt) {
                    const int f = colbase + nt*16 + l15;
                    const float ob = OMEGA_C * res_b2[b*FDIM + f];
                    #pragma unroll
                    for (int j = 0; j < 4; ++j) {
                        const int p = mt*16 + lq*4 + j;
                        const float pre = OMEGA_C * acc[mt][nt][j] + ob;
                        float sv, cv;
                        __sincosf(pre, &sv, &cv);
                        *reinterpret_cast<uint16_t*>(C8 + swz(p, f))
                            = (uint16_t)bfbits(OMEGA_C * cv);
                        mst[mt][nt][j] += sv;
                        acc[mt][nt][j] = mst[mt][nt][j];
                    }
                    __builtin_amdgcn_sched_barrier(0);
                }
        }
        __syncthreads();
        if (wm == 0) {
            #pragma unroll
            for (int mt = 0; mt < 2; ++mt)
                #pragma unroll
                for (int nt = 0; nt < 2; ++nt) {
                    const int f = colbase + nt*16 + l15;
                    #pragma unroll
                    for (int j = 0; j < 4; ++j)
                        *reinterpret_cast<uint16_t*>(A8 + swz(mt*16 + lq*4 + j, f))
                            = (uint16_t)bfbits(acc[mt][nt][j]);
                }
        }
        #pragma unroll
        for (int mt = 0; mt < 4; ++mt) {
            if (wm == 1 || mt >= 2) {
                #pragma unroll
                for (int nt = 0; nt < 2; ++nt) {
                    const int f = colbase + nt*16 + l15;
                    #pragma unroll
                    for (int j = 0; j < 4; ++j) {
                        const int p = (mt & 1)*16 + lq*4 + j;
                        const float cv = u16tof(*reinterpret_cast<const uint16_t*>(C8 + swz(p, f)));
                        mst[mt][nt][j] += cv * acc[mt][nt][j];
                        *reinterpret_cast<uint16_t*>(A8 + swz(rowbase + mt*16 + lq*4 + j, f))
                            = (uint16_t)bfbits(mst[mt][nt][j]);
                    }
                }
                __builtin_amdgcn_sched_barrier(0);
            }
        }
        if (b < NBLK-1) stageW(res_w1 + (b+1)*FDIM*FDIM, 0.5f);   // s=0.5 folded
        __syncthreads();
    }

    // ---- final: out[:,c] = signed combos of dh_k . final_w[row] ----
    // k=0: wr={0,3,2} sg={+,-,+}; k=1: wr={3,0,1} sg={+,+,-}; k=2: wr={2,1,0} sg={-,+,+}
    #pragma unroll
    for (int mt = 0; mt < 4; ++mt) {
        if (wm == 1 || mt >= 2) {
            const int k = 2*wm + (mt >> 1) - 1;   // wave-uniform
            #pragma unroll
            for (int c = 0; c < 3; ++c) {
                int wr; float sg;
                if (c == 0)      { wr = (k==0)?0:(k==1)?3:2; sg = (k==2)?-1.f:1.f; }
                else if (c == 1) { wr = (k==0)?3:(k==1)?0:1; sg = (k==0)?-1.f:1.f; }
                else             { wr = (k==0)?2:(k==1)?1:0; sg = (k==1)?-1.f:1.f; }
                float fwv[2];
                #pragma unroll
                for (int nt = 0; nt < 2; ++nt)
                    fwv[nt] = final_w[wr*FDIM + colbase + nt*16 + l15];
                #pragma unroll
                for (int j = 0; j < 4; ++j) {
                    float part = mst[mt][0][j] * fwv[0] + mst[mt][1][j] * fwv[1];
                    part += __shfl_xor(part, 1);
                    part += __shfl_xor(part, 2);
                    part += __shfl_xor(part, 4);
                    part += __shfl_xor(part, 8);
                    if (l15 == 0) outp[k][wn][(mt & 1)*16 + lq*4 + j][c] = sg * part;
                }
                __builtin_amdgcn_sched_barrier(0);
            }
        }
    }
    __syncthreads();

    if (tid < P_WG * 3) {
        const int p = tid / 3, c = tid % 3;
        float s = 0.f;
        #pragma unroll
        for (int k = 0; k < 3; ++k)
            #pragma unroll
            for (int q = 0; q < 4; ++q) s += outp[k][q][p][c];
        out[(pt0 + p)*3 + c] = s;
    }
}

extern "C" void kernel_launch(void* const* d_in, const int* in_sizes, int n_in,
                              void* d_out, int out_size, void* d_ws, size_t ws_size,
                              hipStream_t stream) {
    const float* coords  = (const float*)d_in[0];
    const float* first_w = (const float*)d_in[1];
    const float* first_b = (const float*)d_in[2];
    const float* res_w1  = (const float*)d_in[3];
    const float* res_b1  = (const float*)d_in[4];
    const float* res_w2  = (const float*)d_in[5];
    const float* res_b2  = (const float*)d_in[6];
    const float* final_w = (const float*)d_in[7];
    // final_b (d_in[8]) does not influence the Jacobian -> unused.

    dim3 grid(NPTS / P_WG);   // 4096 workgroups
    fsrn_kernel<<<grid, NTHR, 0, stream>>>(coords, first_w, first_b,
                                           res_w1, res_b1, res_w2, res_b2,
                                           final_w, (float*)d_out);
}

// Round 8
// 353.030 us; speedup vs baseline: 5.5250x; 3.5085x over previous
//
#include <hip/hip_runtime.h>
#include <hip/hip_bf16.h>
#include <stdint.h>

// fSRN: fused SIREN + 3 forward-mode tangent streams, MFMA engine, v8.
// Two kernels: (1) prep_w converts res_w1/res_w2 -> bf16, folds the 0.5
// scale, and writes the XOR-swizzled LDS image into d_ws (6 x 32 KiB).
// (2) fsrn_kernel: WG = 512 threads (8 waves), 16 points.
// A = 64 rows (4 streams x 16 pts) x 128 cols bf16 (16 KiB, swizzled).
// Wave grid 2x4: wm=wave>>2 -> rows [wm*32,+32) (2 streams), wn=wave&3 ->
// cols [wn*32,+32). Per wave: 2mt x 2nt x 4kk mfma 16x16x32.
// Per-thread state: mst[2][2][4]=16 f32 + acc[2][2]=16 f32  (v7 post-mortem:
// launch_bounds cap 128 total was split 64 arch + 64 AGPR by the compiler;
// 64-float state overflowed the 64 arch regs -> deterministic spill. 32
// floats fits either side of any split.)
// stageW = linear 16B copies of the pre-swizzled image (no conversion VALU).
// LDS ~54.7 KiB -> 2 WGs/CU (independent barrier domains).

#define OMEGA_C 30.0f

constexpr int NPTS = 131072;
constexpr int FDIM = 128;
constexpr int NBLK = 3;
constexpr int P_WG = 16;
constexpr int NTHR = 512;   // 8 waves

typedef short bf16x8 __attribute__((ext_vector_type(8)));
typedef float f32x4  __attribute__((ext_vector_type(4)));

__device__ __forceinline__ uint16_t f2bf(float f) {
    __hip_bfloat16 h = __float2bfloat16(f);     // HW RNE
    return __builtin_bit_cast(uint16_t, h);
}
__device__ __forceinline__ float bf2f(uint16_t u) {
    return __bfloat162float(__builtin_bit_cast(__hip_bfloat16, u));
}

// swizzled byte offset into a [rows][128] bf16 tile with 256 B rows:
// 16B chunk index XORed with (row & 15).
__device__ __forceinline__ int swz(int row, int col) {
    const int b = col << 1;
    return (row << 8) + ((((b >> 4) ^ (row & 15)) << 4) | (b & 15));
}

// ---- kernel 1: weights -> bf16, scale folded, swizzled image in ws ----
// tile t (0..5) = {w1[0], w2[0], 0.5*w1[1], w2[1], 0.5*w1[2], w2[2]}
__global__ void prep_w_kernel(const float* __restrict__ res_w1,
                              const float* __restrict__ res_w2,
                              uint16_t* __restrict__ ws) {
    const int t = blockIdx.x;
    const int b = t >> 1, l = t & 1;
    const float scale = (l == 0 && b > 0) ? 0.5f : 1.0f;
    const float* src = (l == 0 ? res_w1 : res_w2) + b * FDIM * FDIM;
    uint8_t* dst = reinterpret_cast<uint8_t*>(ws + t * 16384);
    #pragma unroll
    for (int i = 0; i < 8; ++i) {
        const int g   = (int)threadIdx.x + (i << 8);   // chunk 0..2047 (8 bf16 each)
        const int row = g >> 4, c = g & 15;
        const float4 v0 = *reinterpret_cast<const float4*>(src + (g << 3));
        const float4 v1 = *reinterpret_cast<const float4*>(src + (g << 3) + 4);
        uint4 w;
        w.x = (uint32_t)f2bf(scale * v0.x) | ((uint32_t)f2bf(scale * v0.y) << 16);
        w.y = (uint32_t)f2bf(scale * v0.z) | ((uint32_t)f2bf(scale * v0.w) << 16);
        w.z = (uint32_t)f2bf(scale * v1.x) | ((uint32_t)f2bf(scale * v1.y) << 16);
        w.w = (uint32_t)f2bf(scale * v1.z) | ((uint32_t)f2bf(scale * v1.w) << 16);
        *reinterpret_cast<uint4*>(dst + (row << 8) + ((c ^ (row & 15)) << 4)) = w;
    }
}

// ---- kernel 2: the fused network ----
__global__ __launch_bounds__(NTHR, 4) void fsrn_kernel(
    const float* __restrict__ coords,
    const float* __restrict__ first_w,
    const float* __restrict__ first_b,
    const float* __restrict__ res_b1,
    const float* __restrict__ res_b2,
    const float* __restrict__ final_w,
    const uint16_t* __restrict__ ws,
    float* __restrict__ out)
{
    __shared__ __align__(16) uint8_t A8[64 * 256];    // 16 KiB activations
    __shared__ __align__(16) uint8_t W8[128 * 256];   // 32 KiB weights
    __shared__ __align__(16) uint8_t C8[16 * 256];    //  4 KiB OMEGA*cos
    __shared__ float xyz[P_WG * 3];                   // 192 B
    __shared__ float outp[3][4][P_WG][3];             // 2304 B

    const int tid  = threadIdx.x;
    const int wave = tid >> 6;
    const int lane = tid & 63;
    const int l15  = lane & 15;
    const int lq   = lane >> 4;            // 0..3
    const int wm   = wave >> 2;            // 0: rows 0..31 (h, dhx), 1: rows 32..63 (dhy, dhz)
    const int wn   = wave & 3;             // col quarter
    const int rowbase = wm * 32;
    const int colbase = wn * 32;
    const int pt0  = blockIdx.x * P_WG;

    float mst[2][2][4];    // fp32 masters [mt][nt][j] — static idx ONLY
    f32x4 acc[2][2];       // MFMA accumulators [mt][nt] — static idx ONLY

    if (tid < P_WG * 3) xyz[tid] = coords[pt0 * 3 + tid];

    // linear copy of pre-swizzled 32 KiB tile into W8
    auto stageW = [&](int t) {
        const uint4* src = reinterpret_cast<const uint4*>(ws + t * 16384) + tid;
        #pragma unroll
        for (int i = 0; i < 4; ++i)
            *reinterpret_cast<uint4*>(W8 + ((tid + (i << 9)) << 4)) = src[i << 9];
    };

    stageW(0);
    __syncthreads();                 // xyz + W8(tile0) visible

    // ---- first layer ----
    #pragma unroll
    for (int mt = 0; mt < 2; ++mt) {
        const int s_mt = 2*wm + mt;          // stream of these 16 rows
        #pragma unroll
        for (int nt = 0; nt < 2; ++nt) {
            const int f = colbase + nt*16 + l15;
            const float w0 = first_w[f*3+0], w1 = first_w[f*3+1], w2 = first_w[f*3+2];
            const float fb = first_b[f];
            const float wk = (s_mt == 1) ? w0 : (s_mt == 2) ? w1 : w2;
            #pragma unroll
            for (int j = 0; j < 4; ++j) {
                const int p = lq*4 + j;
                const float pre = OMEGA_C * (xyz[p*3]*w0 + xyz[p*3+1]*w1 + xyz[p*3+2]*w2 + fb);
                const float v = (s_mt == 0) ? __sinf(pre) : OMEGA_C * __cosf(pre) * wk;
                mst[mt][nt][j] = v;
                *reinterpret_cast<uint16_t*>(A8 + swz(rowbase + mt*16 + p, f)) = f2bf(v);
            }
        }
    }
    __syncthreads();

    auto gemm = [&]() {
        #pragma unroll
        for (int mt = 0; mt < 2; ++mt)
            #pragma unroll
            for (int nt = 0; nt < 2; ++nt) acc[mt][nt] = f32x4{0.f,0.f,0.f,0.f};
        #pragma unroll
        for (int kk = 0; kk < 4; ++kk) {
            bf16x8 af0 = *reinterpret_cast<const bf16x8*>(
                A8 + swz(rowbase + l15, kk*32 + lq*8));
            bf16x8 af1 = *reinterpret_cast<const bf16x8*>(
                A8 + swz(rowbase + 16 + l15, kk*32 + lq*8));
            #pragma unroll
            for (int nt = 0; nt < 2; ++nt) {
                const bf16x8 wf = *reinterpret_cast<const bf16x8*>(
                    W8 + swz(colbase + nt*16 + l15, kk*32 + lq*8));
                acc[0][nt] = __builtin_amdgcn_mfma_f32_16x16x32_bf16(af0, wf, acc[0][nt], 0, 0, 0);
                acc[1][nt] = __builtin_amdgcn_mfma_f32_16x16x32_bf16(af1, wf, acc[1][nt], 0, 0, 0);
            }
        }
    };

    #pragma unroll 1
    for (int b = 0; b < NBLK; ++b) {
        // ================= sub-layer 1: W = s*w1[b] (tile 2b) =================
        gemm();
        if (wm == 0) {   // primal rows (mt 0): sincos; publish cos; stage sin in acc
            #pragma unroll
            for (int nt = 0; nt < 2; ++nt) {
                const int f = colbase + nt*16 + l15;
                const float ob = OMEGA_C * res_b1[b*FDIM + f];
                #pragma unroll
                for (int j = 0; j < 4; ++j) {
                    const int p = lq*4 + j;
                    const float pre = OMEGA_C * acc[0][nt][j] + ob;
                    float sv, cv;
                    __sincosf(pre, &sv, &cv);
                    *reinterpret_cast<uint16_t*>(C8 + swz(p, f)) = f2bf(OMEGA_C * cv);
                    acc[0][nt][j] = sv;
                }
            }
        }
        __syncthreads();   // gemm A8/W8 reads done; C8 visible
        if (wm == 0) {
            #pragma unroll
            for (int nt = 0; nt < 2; ++nt) {
                const int f = colbase + nt*16 + l15;
                #pragma unroll
                for (int j = 0; j < 4; ++j) {
                    const int p = lq*4 + j;
                    *reinterpret_cast<uint16_t*>(A8 + swz(p, f)) = f2bf(acc[0][nt][j]);
                    const float cv = bf2f(*reinterpret_cast<const uint16_t*>(C8 + swz(p, f)));
                    *reinterpret_cast<uint16_t*>(A8 + swz(16 + p, f)) = f2bf(cv * acc[1][nt][j]);
                }
            }
        } else {
            #pragma unroll
            for (int mt = 0; mt < 2; ++mt)
                #pragma unroll
                for (int nt = 0; nt < 2; ++nt) {
                    const int f = colbase + nt*16 + l15;
                    #pragma unroll
                    for (int j = 0; j < 4; ++j) {
                        const int p = lq*4 + j;
                        const float cv = bf2f(*reinterpret_cast<const uint16_t*>(C8 + swz(p, f)));
                        *reinterpret_cast<uint16_t*>(A8 + swz(rowbase + mt*16 + p, f))
                            = f2bf(cv * acc[mt][nt][j]);
                    }
                }
        }
        stageW(2*b + 1);
        __syncthreads();

        // ================= sub-layer 2: W = w2[b] (tile 2b+1), residual ======
        gemm();
        if (wm == 0) {
            #pragma unroll
            for (int nt = 0; nt < 2; ++nt) {
                const int f = colbase + nt*16 + l15;
                const float ob = OMEGA_C * res_b2[b*FDIM + f];
                #pragma unroll
                for (int j = 0; j < 4; ++j) {
                    const int p = lq*4 + j;
                    const float pre = OMEGA_C * acc[0][nt][j] + ob;
                    float sv, cv;
                    __sincosf(pre, &sv, &cv);
                    *reinterpret_cast<uint16_t*>(C8 + swz(p, f)) = f2bf(OMEGA_C * cv);
                    mst[0][nt][j] += sv;
                    acc[0][nt][j] = mst[0][nt][j];
                }
            }
        }
        __syncthreads();
        if (wm == 0) {
            #pragma unroll
            for (int nt = 0; nt < 2; ++nt) {
                const int f = colbase + nt*16 + l15;
                #pragma unroll
                for (int j = 0; j < 4; ++j) {
                    const int p = lq*4 + j;
                    *reinterpret_cast<uint16_t*>(A8 + swz(p, f)) = f2bf(acc[0][nt][j]);
                    const float cv = bf2f(*reinterpret_cast<const uint16_t*>(C8 + swz(p, f)));
                    mst[1][nt][j] += cv * acc[1][nt][j];
                    *reinterpret_cast<uint16_t*>(A8 + swz(16 + p, f)) = f2bf(mst[1][nt][j]);
                }
            }
        } else {
            #pragma unroll
            for (int mt = 0; mt < 2; ++mt)
                #pragma unroll
                for (int nt = 0; nt < 2; ++nt) {
                    const int f = colbase + nt*16 + l15;
                    #pragma unroll
                    for (int j = 0; j < 4; ++j) {
                        const int p = lq*4 + j;
                        const float cv = bf2f(*reinterpret_cast<const uint16_t*>(C8 + swz(p, f)));
                        mst[mt][nt][j] += cv * acc[mt][nt][j];
                        *reinterpret_cast<uint16_t*>(A8 + swz(rowbase + mt*16 + p, f))
                            = f2bf(mst[mt][nt][j]);
                    }
                }
        }
        if (b < NBLK-1) stageW(2*b + 2);
        __syncthreads();
    }

    // ---- final: out[:,c] = signed combos of dh_k . final_w[row] ----
    // k=0: wr={0,3,2} sg={+,-,+}; k=1: wr={3,0,1} sg={+,+,-}; k=2: wr={2,1,0} sg={-,+,+}
    #pragma unroll
    for (int mt = 0; mt < 2; ++mt) {
        if (wm == 1 || mt == 1) {
            const int k = 2*wm + mt - 1;       // wave-uniform tangent index
            #pragma unroll
            for (int c = 0; c < 3; ++c) {
                int wr; float sg;
                if (c == 0)      { wr = (k==0)?0:(k==1)?3:2; sg = (k==2)?-1.f:1.f; }
                else if (c == 1) { wr = (k==0)?3:(k==1)?0:1; sg = (k==0)?-1.f:1.f; }
                else             { wr = (k==0)?2:(k==1)?1:0; sg = (k==1)?-1.f:1.f; }
                const float fw0 = final_w[wr*FDIM + colbase + l15];
                const float fw1 = final_w[wr*FDIM + colbase + 16 + l15];
                #pragma unroll
                for (int j = 0; j < 4; ++j) {
                    float part = mst[mt][0][j] * fw0 + mst[mt][1][j] * fw1;
                    part += __shfl_xor(part, 1);
                    part += __shfl_xor(part, 2);
                    part += __shfl_xor(part, 4);
                    part += __shfl_xor(part, 8);
                    if (l15 == 0) outp[k][wn][lq*4 + j][c] = sg * part;
                }
            }
        }
    }
    __syncthreads();

    if (tid < P_WG * 3) {
        const int p = tid / 3, c = tid % 3;
        float s = 0.f;
        #pragma unroll
        for (int k = 0; k < 3; ++k)
            #pragma unroll
            for (int q = 0; q < 4; ++q) s += outp[k][q][p][c];
        out[(pt0 + p)*3 + c] = s;
    }
}

extern "C" void kernel_launch(void* const* d_in, const int* in_sizes, int n_in,
                              void* d_out, int out_size, void* d_ws, size_t ws_size,
                              hipStream_t stream) {
    const float* coords  = (const float*)d_in[0];
    const float* first_w = (const float*)d_in[1];
    const float* first_b = (const float*)d_in[2];
    const float* res_w1  = (const float*)d_in[3];
    const float* res_b1  = (const float*)d_in[4];
    const float* res_w2  = (const float*)d_in[5];
    const float* res_b2  = (const float*)d_in[6];
    const float* final_w = (const float*)d_in[7];
    // final_b (d_in[8]) does not influence the Jacobian -> unused.
    uint16_t* ws = (uint16_t*)d_ws;    // 6 x 16384 bf16 = 192 KiB

    prep_w_kernel<<<dim3(6), dim3(256), 0, stream>>>(res_w1, res_w2, ws);
    fsrn_kernel<<<dim3(NPTS / P_WG), dim3(NTHR), 0, stream>>>(
        coords, first_w, first_b, res_b1, res_b2, final_w, ws, (float*)d_out);
}

// Round 10
// 327.380 us; speedup vs baseline: 5.9579x; 1.0783x over previous
//
#include <hip/hip_runtime.h>
#include <hip/hip_bf16.h>
#include <stdint.h>

// fSRN: fused SIREN + 3 forward-mode tangent streams, MFMA engine, v10.
// v10 = v8 (VERIFIED: 325 us, absmax 0.015625) + ONE isolated change:
//   W no longer staged in LDS. prep_w_kernel writes a fragment-ordered bf16
//   image (frag(t,wn,kk,nt,lane), 16 B per lane) into d_ws; gemm loads W
//   fragments straight from L2 (192 KB, resident; coalesced 1KB/wave-load).
//   Removes the 32 KiB W8 buffer + all stageW copies -> LDS 55.8 -> ~22.4
//   KiB -> 4 WGs/CU = 32 waves/CU (was 16). Everything else is v8
//   byte-identical: stream-major A rows, C8 cos exchange, wm wave roles.
// (v9 bundled this W change with a point-major rewrite and failed 0.52;
//  this round isolates the W path on the known-good base.)
//
// Geometry (v8): WG = 512 thr (8 waves), P_WG = 16 points.
// A = 64 rows (4 streams x 16 pts: rows 0..15 h, 16..31 dhx, 32..47 dhy,
// 48..63 dhz) x 128 cols bf16, XOR-swizzled. Wave (wm = wave>>2, wn = wave&3)
// computes rows [wm*32,+32) x cols [wn*32,+32): 2mt x 2nt x 4kk mfma 16x16x32.
// Per-thread state: mst[2][2][4] + acc[2][2] = 32 f32 (no spill at 128-cap).

#define OMEGA_C 30.0f

constexpr int NPTS = 131072;
constexpr int FDIM = 128;
constexpr int NBLK = 3;
constexpr int P_WG = 16;
constexpr int NTHR = 512;   // 8 waves

typedef short bf16x8 __attribute__((ext_vector_type(8)));
typedef float f32x4  __attribute__((ext_vector_type(4)));

__device__ __forceinline__ uint16_t f2bf(float f) {
    __hip_bfloat16 h = __float2bfloat16(f);     // HW RNE
    return __builtin_bit_cast(uint16_t, h);
}
__device__ __forceinline__ float bf2f(uint16_t u) {
    return __bfloat162float(__builtin_bit_cast(__hip_bfloat16, u));
}

// swizzled byte offset into a [rows][128] bf16 tile with 256 B rows:
// 16B chunk index XORed with (row & 15).
__device__ __forceinline__ int swz(int row, int col) {
    const int b = col << 1;
    return (row << 8) + ((((b >> 4) ^ (row & 15)) << 4) | (b & 15));
}

// ---- kernel 1: weights -> bf16 fragment image in ws ----
// tile t (0..5) = {w1[0], w2[0], 0.5*w1[1], w2[1], 0.5*w1[2], w2[2]}
// frag flat id = (t*4+wn)*512 + kk*128 + nt*64 + lane   (uint4 units)
// content: W[col][k0..k0+8), col = wn*32+nt*16+(lane&15), k0 = kk*32+(lane>>4)*8
__global__ void prep_w_kernel(const float* __restrict__ res_w1,
                              const float* __restrict__ res_w2,
                              uint4* __restrict__ ws) {
    const int t = blockIdx.x;
    const int b = t >> 1, l = t & 1;
    const float scale = (l == 0 && b > 0) ? 0.5f : 1.0f;
    const float* src = (l == 0 ? res_w1 : res_w2) + b * FDIM * FDIM;
    #pragma unroll
    for (int i = 0; i < 8; ++i) {
        const int g    = (int)threadIdx.x + (i << 8);   // 0..2047 within tile
        const int lane = g & 63;
        const int nt   = (g >> 6) & 1;
        const int kk   = (g >> 7) & 3;
        const int wn   = g >> 9;
        const int col  = wn*32 + nt*16 + (lane & 15);
        const int k0   = kk*32 + (lane >> 4) * 8;
        const float4 v0 = *reinterpret_cast<const float4*>(src + col*FDIM + k0);
        const float4 v1 = *reinterpret_cast<const float4*>(src + col*FDIM + k0 + 4);
        uint4 w;
        w.x = (uint32_t)f2bf(scale*v0.x) | ((uint32_t)f2bf(scale*v0.y) << 16);
        w.y = (uint32_t)f2bf(scale*v0.z) | ((uint32_t)f2bf(scale*v0.w) << 16);
        w.z = (uint32_t)f2bf(scale*v1.x) | ((uint32_t)f2bf(scale*v1.y) << 16);
        w.w = (uint32_t)f2bf(scale*v1.z) | ((uint32_t)f2bf(scale*v1.w) << 16);
        ws[t*2048 + g] = w;
    }
}

// ---- kernel 2: the fused network ----
__global__ __launch_bounds__(NTHR, 4) void fsrn_kernel(
    const float* __restrict__ coords,
    const float* __restrict__ first_w,
    const float* __restrict__ first_b,
    const float* __restrict__ res_b1,
    const float* __restrict__ res_b2,
    const float* __restrict__ final_w,
    const uint4* __restrict__ ws,
    float* __restrict__ out)
{
    __shared__ __align__(16) uint8_t A8[64 * 256];    // 16 KiB activations
    __shared__ __align__(16) uint8_t C8[16 * 256];    //  4 KiB OMEGA*cos
    __shared__ float xyz[P_WG * 3];                   // 192 B
    __shared__ float outp[3][4][P_WG][3];             // 2304 B

    const int tid  = threadIdx.x;
    const int wave = tid >> 6;
    const int lane = tid & 63;
    const int l15  = lane & 15;
    const int lq   = lane >> 4;            // 0..3
    const int wm   = wave >> 2;            // 0: rows 0..31 (h, dhx), 1: rows 32..63 (dhy, dhz)
    const int wn   = wave & 3;             // col quarter
    const int rowbase = wm * 32;
    const int colbase = wn * 32;
    const int pt0  = blockIdx.x * P_WG;

    float mst[2][2][4];    // fp32 masters [mt][nt][j] — static idx ONLY
    f32x4 acc[2][2];       // MFMA accumulators [mt][nt] — static idx ONLY

    if (tid < P_WG * 3) xyz[tid] = coords[pt0 * 3 + tid];
    __syncthreads();

    // ---- first layer ----
    #pragma unroll
    for (int mt = 0; mt < 2; ++mt) {
        const int s_mt = 2*wm + mt;          // stream of these 16 rows
        #pragma unroll
        for (int nt = 0; nt < 2; ++nt) {
            const int f = colbase + nt*16 + l15;
            const float w0 = first_w[f*3+0], w1 = first_w[f*3+1], w2 = first_w[f*3+2];
            const float fb = first_b[f];
            const float wk = (s_mt == 1) ? w0 : (s_mt == 2) ? w1 : w2;
            #pragma unroll
            for (int j = 0; j < 4; ++j) {
                const int p = lq*4 + j;
                const float pre = OMEGA_C * (xyz[p*3]*w0 + xyz[p*3+1]*w1 + xyz[p*3+2]*w2 + fb);
                const float v = (s_mt == 0) ? __sinf(pre) : OMEGA_C * __cosf(pre) * wk;
                mst[mt][nt][j] = v;
                *reinterpret_cast<uint16_t*>(A8 + swz(rowbase + mt*16 + p, f)) = f2bf(v);
            }
        }
    }
    __syncthreads();

    // GEMM vs W-tile t (fragments from L2; same math as v8's LDS version)
    auto gemm = [&](int t) {
        #pragma unroll
        for (int mt = 0; mt < 2; ++mt)
            #pragma unroll
            for (int nt = 0; nt < 2; ++nt) acc[mt][nt] = f32x4{0.f,0.f,0.f,0.f};
        const uint4* wbase = ws + (t*4 + wn)*512 + lane;
        #pragma unroll
        for (int kk = 0; kk < 4; ++kk) {
            const uint4 wq0 = wbase[kk*128];
            const uint4 wq1 = wbase[kk*128 + 64];
            const bf16x8 wf0 = __builtin_bit_cast(bf16x8, wq0);
            const bf16x8 wf1 = __builtin_bit_cast(bf16x8, wq1);
            const bf16x8 af0 = *reinterpret_cast<const bf16x8*>(
                A8 + swz(rowbase + l15, kk*32 + lq*8));
            const bf16x8 af1 = *reinterpret_cast<const bf16x8*>(
                A8 + swz(rowbase + 16 + l15, kk*32 + lq*8));
            acc[0][0] = __builtin_amdgcn_mfma_f32_16x16x32_bf16(af0, wf0, acc[0][0], 0, 0, 0);
            acc[0][1] = __builtin_amdgcn_mfma_f32_16x16x32_bf16(af0, wf1, acc[0][1], 0, 0, 0);
            acc[1][0] = __builtin_amdgcn_mfma_f32_16x16x32_bf16(af1, wf0, acc[1][0], 0, 0, 0);
            acc[1][1] = __builtin_amdgcn_mfma_f32_16x16x32_bf16(af1, wf1, acc[1][1], 0, 0, 0);
        }
    };

    #pragma unroll 1
    for (int b = 0; b < NBLK; ++b) {
        // ================= sub-layer 1: W = s*w1[b] (tile 2b) =================
        gemm(2*b);
        if (wm == 0) {   // primal rows (mt 0): sincos; publish cos; stage sin in acc
            #pragma unroll
            for (int nt = 0; nt < 2; ++nt) {
                const int f = colbase + nt*16 + l15;
                const float ob = OMEGA_C * res_b1[b*FDIM + f];
                #pragma unroll
                for (int j = 0; j < 4; ++j) {
                    const int p = lq*4 + j;
                    const float pre = OMEGA_C * acc[0][nt][j] + ob;
                    float sv, cv;
                    __sincosf(pre, &sv, &cv);
                    *reinterpret_cast<uint16_t*>(C8 + swz(p, f)) = f2bf(OMEGA_C * cv);
                    acc[0][nt][j] = sv;
                }
            }
        }
        __syncthreads();   // gemm A8 reads done; C8 visible
        if (wm == 0) {
            #pragma unroll
            for (int nt = 0; nt < 2; ++nt) {
                const int f = colbase + nt*16 + l15;
                #pragma unroll
                for (int j = 0; j < 4; ++j) {
                    const int p = lq*4 + j;
                    *reinterpret_cast<uint16_t*>(A8 + swz(p, f)) = f2bf(acc[0][nt][j]);
                    const float cv = bf2f(*reinterpret_cast<const uint16_t*>(C8 + swz(p, f)));
                    *reinterpret_cast<uint16_t*>(A8 + swz(16 + p, f)) = f2bf(cv * acc[1][nt][j]);
                }
            }
        } else {
            #pragma unroll
            for (int mt = 0; mt < 2; ++mt)
                #pragma unroll
                for (int nt = 0; nt < 2; ++nt) {
                    const int f = colbase + nt*16 + l15;
                    #pragma unroll
                    for (int j = 0; j < 4; ++j) {
                        const int p = lq*4 + j;
                        const float cv = bf2f(*reinterpret_cast<const uint16_t*>(C8 + swz(p, f)));
                        *reinterpret_cast<uint16_t*>(A8 + swz(rowbase + mt*16 + p, f))
                            = f2bf(cv * acc[mt][nt][j]);
                    }
                }
        }
        __syncthreads();

        // ================= sub-layer 2: W = w2[b] (tile 2b+1), residual ======
        gemm(2*b + 1);
        if (wm == 0) {
            #pragma unroll
            for (int nt = 0; nt < 2; ++nt) {
                const int f = colbase + nt*16 + l15;
                const float ob = OMEGA_C * res_b2[b*FDIM + f];
                #pragma unroll
                for (int j = 0; j < 4; ++j) {
                    const int p = lq*4 + j;
                    const float pre = OMEGA_C * acc[0][nt][j] + ob;
                    float sv, cv;
                    __sincosf(pre, &sv, &cv);
                    *reinterpret_cast<uint16_t*>(C8 + swz(p, f)) = f2bf(OMEGA_C * cv);
                    mst[0][nt][j] += sv;
                    acc[0][nt][j] = mst[0][nt][j];
                }
            }
        }
        __syncthreads();
        if (wm == 0) {
            #pragma unroll
            for (int nt = 0; nt < 2; ++nt) {
                const int f = colbase + nt*16 + l15;
                #pragma unroll
                for (int j = 0; j < 4; ++j) {
                    const int p = lq*4 + j;
                    *reinterpret_cast<uint16_t*>(A8 + swz(p, f)) = f2bf(acc[0][nt][j]);
                    const float cv = bf2f(*reinterpret_cast<const uint16_t*>(C8 + swz(p, f)));
                    mst[1][nt][j] += cv * acc[1][nt][j];
                    *reinterpret_cast<uint16_t*>(A8 + swz(16 + p, f)) = f2bf(mst[1][nt][j]);
                }
            }
        } else {
            #pragma unroll
            for (int mt = 0; mt < 2; ++mt)
                #pragma unroll
                for (int nt = 0; nt < 2; ++nt) {
                    const int f = colbase + nt*16 + l15;
                    #pragma unroll
                    for (int j = 0; j < 4; ++j) {
                        const int p = lq*4 + j;
                        const float cv = bf2f(*reinterpret_cast<const uint16_t*>(C8 + swz(p, f)));
                        mst[mt][nt][j] += cv * acc[mt][nt][j];
                        *reinterpret_cast<uint16_t*>(A8 + swz(rowbase + mt*16 + p, f))
                            = f2bf(mst[mt][nt][j]);
                    }
                }
        }
        __syncthreads();
    }

    // ---- final: out[:,c] = signed combos of dh_k . final_w[row] ----
    // k=0: wr={0,3,2} sg={+,-,+}; k=1: wr={3,0,1} sg={+,+,-}; k=2: wr={2,1,0} sg={-,+,+}
    #pragma unroll
    for (int mt = 0; mt < 2; ++mt) {
        if (wm == 1 || mt == 1) {
            const int k = 2*wm + mt - 1;       // wave-uniform tangent index
            #pragma unroll
            for (int c = 0; c < 3; ++c) {
                int wr; float sg;
                if (c == 0)      { wr = (k==0)?0:(k==1)?3:2; sg = (k==2)?-1.f:1.f; }
                else if (c == 1) { wr = (k==0)?3:(k==1)?0:1; sg = (k==0)?-1.f:1.f; }
                else             { wr = (k==0)?2:(k==1)?1:0; sg = (k==1)?-1.f:1.f; }
                const float fw0 = final_w[wr*FDIM + colbase + l15];
                const float fw1 = final_w[wr*FDIM + colbase + 16 + l15];
                #pragma unroll
                for (int j = 0; j < 4; ++j) {
                    float part = mst[mt][0][j] * fw0 + mst[mt][1][j] * fw1;
                    part += __shfl_xor(part, 1);
                    part += __shfl_xor(part, 2);
                    part += __shfl_xor(part, 4);
                    part += __shfl_xor(part, 8);
                    if (l15 == 0) outp[k][wn][lq*4 + j][c] = sg * part;
                }
            }
        }
    }
    __syncthreads();

    if (tid < P_WG * 3) {
        const int p = tid / 3, c = tid % 3;
        float s = 0.f;
        #pragma unroll
        for (int k = 0; k < 3; ++k)
            #pragma unroll
            for (int q = 0; q < 4; ++q) s += outp[k][q][p][c];
        out[(pt0 + p)*3 + c] = s;
    }
}

extern "C" void kernel_launch(void* const* d_in, const int* in_sizes, int n_in,
                              void* d_out, int out_size, void* d_ws, size_t ws_size,
                              hipStream_t stream) {
    const float* coords  = (const float*)d_in[0];
    const float* first_w = (const float*)d_in[1];
    const float* first_b = (const float*)d_in[2];
    const float* res_w1  = (const float*)d_in[3];
    const float* res_b1  = (const float*)d_in[4];
    const float* res_w2  = (const float*)d_in[5];
    const float* res_b2  = (const float*)d_in[6];
    const float* final_w = (const float*)d_in[7];
    // final_b (d_in[8]) does not influence the Jacobian -> unused.
    uint4* ws = (uint4*)d_ws;   // 12288 x 16 B = 192 KiB fragment image

    prep_w_kernel<<<dim3(6), dim3(256), 0, stream>>>(res_w1, res_w2, ws);
    fsrn_kernel<<<dim3(NPTS / P_WG), dim3(NTHR), 0, stream>>>(
        coords, first_w, first_b, res_b1, res_b2, final_w, ws, (float*)d_out);
}